// Round 7
// baseline (616.447 us; speedup 1.0000x reference)
//
#include <hip/hip_runtime.h>

#define TT 4096
#define HD 2048
#define FD 768
#define NE 32
#define TOPK 4
#define NSG 8
#define CAPE 1024
#define MAXTILES 160
#define UPGRID (MAXTILES * 12)
#define DNGRID (MAXTILES * 16)

typedef __attribute__((ext_vector_type(8))) short short8;
typedef __attribute__((ext_vector_type(4))) float f32x4;
typedef __attribute__((ext_vector_type(4))) unsigned short us4;
typedef __attribute__((ext_vector_type(8))) unsigned short us8;

__device__ __forceinline__ unsigned short f2bf(float f) {
  unsigned u = __builtin_bit_cast(unsigned, f);
  u += 0x7FFFu + ((u >> 16) & 1u);
  return (unsigned short)(u >> 16);
}
__device__ __forceinline__ float bf2f(unsigned short b) {
  return __builtin_bit_cast(float, (unsigned)b << 16);
}

__device__ __forceinline__ void async16(const void* g, void* l) {
  __builtin_amdgcn_global_load_lds(
      (const __attribute__((address_space(1))) unsigned int*)g,
      (__attribute__((address_space(3))) unsigned int*)l, 16, 0, 0);
}

// ---------------- w_router [H][E] -> wrt [E][H] (fp32, tiny) ----------------
__global__ __launch_bounds__(256) void wrt_kernel(const float* __restrict__ w_router,
                                                  float* __restrict__ wrt) {
  int idx = blockIdx.x * 256 + threadIdx.x;
  int e = idx >> 11, h = idx & 2047;
  wrt[idx] = w_router[h * NE + e];
}

// -------- logits fp32 GEMM + fused top-4/softmax: [16 tok/block] x [32 experts] --------
#define LSTR 68
__global__ __launch_bounds__(256) void logits_kernel(
    const float* __restrict__ rin, const float* __restrict__ wrt,
    float* __restrict__ top_logits, int* __restrict__ sel, float* __restrict__ rwts) {
  __shared__ float As[16 * LSTR];
  __shared__ float Bs[32 * LSTR];
  __shared__ float lgS[16][33];
  const int tid = threadIdx.x;
  const int t0 = blockIdx.x * 16;
  const int tp = tid >> 4, eg = tid & 15;
  f32x4 acc0 = (f32x4)0.f, acc1 = (f32x4)0.f;
  for (int kt = 0; kt < HD; kt += 64) {
    __syncthreads();
    {
      int row = tid >> 4, col = (tid & 15) * 4;
      *(f32x4*)&As[row * LSTR + col] =
          *(const f32x4*)&rin[(size_t)(t0 + row) * HD + kt + col];
    }
    {
      int e = tid >> 3, col = (tid & 7) * 8;
      *(f32x4*)&Bs[e * LSTR + col] = *(const f32x4*)&wrt[(size_t)e * HD + kt + col];
      *(f32x4*)&Bs[e * LSTR + col + 4] =
          *(const f32x4*)&wrt[(size_t)e * HD + kt + col + 4];
    }
    __syncthreads();
#pragma unroll
    for (int k4 = 0; k4 < 16; ++k4) {
      f32x4 a = *(const f32x4*)&As[tp * LSTR + k4 * 4];
      f32x4 b0 = *(const f32x4*)&Bs[eg * LSTR + k4 * 4];
      f32x4 b1 = *(const f32x4*)&Bs[(eg + 16) * LSTR + k4 * 4];
      acc0 += a * b0;
      acc1 += a * b1;
    }
  }
  lgS[tp][eg] = acc0[0] + acc0[1] + acc0[2] + acc0[3];
  lgS[tp][eg + 16] = acc1[0] + acc1[1] + acc1[2] + acc1[3];
  __syncthreads();
  if (tid < 16) {
    const float* row = lgS[tid];
    float val[TOPK];
    int idx[TOPK];
    unsigned used = 0;
#pragma unroll
    for (int k = 0; k < TOPK; ++k) {
      float best = -1e30f;
      int bi = 0;
      for (int e = 0; e < NE; ++e) {
        float v = row[e];
        if (!((used >> e) & 1u) && v > best) { best = v; bi = e; }
      }
      used |= 1u << bi;
      val[k] = best;
      idx[k] = bi;
    }
    float ex[TOPK], sum = 0.f;
#pragma unroll
    for (int k = 0; k < TOPK; ++k) { ex[k] = expf(val[k] - val[0]); sum += ex[k]; }
    int t = t0 + tid;
#pragma unroll
    for (int k = 0; k < TOPK; ++k) {
      top_logits[t * TOPK + k] = val[k];
      sel[t * TOPK + k] = idx[k];
      rwts[t * TOPK + k] = ex[k] / sum;
    }
  }
}

// ---------------- dispatch: ordered compaction per expert + slot map ----------------
__global__ __launch_bounds__(256) void dispatch_kernel(
    const int* __restrict__ sel, const float* __restrict__ rwts,
    int* __restrict__ tok_idx, float* __restrict__ tok_w, int* __restrict__ counts,
    int* __restrict__ slotmap) {
  const int e = blockIdx.x;
  __shared__ int wcnt[4];
  __shared__ int base;
  const int tid = threadIdx.x, lane = tid & 63, wid = tid >> 6;
  if (tid == 0) base = 0;
  __syncthreads();
  for (int t0 = 0; t0 < TT; t0 += 256) {
    int t = t0 + tid;
    int hitk = -1;
#pragma unroll
    for (int k = 0; k < TOPK; ++k)
      if (sel[t * TOPK + k] == e) hitk = k;
    unsigned long long m = __ballot(hitk >= 0);
    if (lane == 0) wcnt[wid] = __popcll(m);
    __syncthreads();
    int off = base;
    for (int w = 0; w < wid; ++w) off += wcnt[w];
    int pos = off + __popcll(m & ((1ULL << lane) - 1ULL));
    if (hitk >= 0) {
      if (pos < CAPE) {
        tok_idx[e * CAPE + pos] = t;
        tok_w[e * CAPE + pos] = rwts[t * TOPK + hitk];
        slotmap[t * TOPK + hitk] = e * CAPE + pos;
      } else {
        slotmap[t * TOPK + hitk] = -1;
      }
    }
    __syncthreads();
    if (tid == 0) base += wcnt[0] + wcnt[1] + wcnt[2] + wcnt[3];
    __syncthreads();
  }
  if (tid == 0) counts[e] = base < CAPE ? base : CAPE;
}

// ---------------- tile work-list builder (deterministic order) ----------------
__global__ void build_tiles_kernel(const int* __restrict__ counts,
                                   int* __restrict__ tlist, int* __restrict__ ntiles) {
  if (threadIdx.x == 0) {
    int n = 0;
    for (int e = 0; e < NE; ++e) {
      int c = counts[e];
      int mb = (c + 127) >> 7;
      for (int m = 0; m < mb; ++m) tlist[n++] = (e << 8) | m;
    }
    ntiles[0] = n;
  }
}

// ---------------- secondary gate per (expert, slot) ----------------
__global__ __launch_bounds__(256) void sgate_kernel(
    const float* __restrict__ rin, const float* __restrict__ w_sgate,
    const int* __restrict__ tok_idx, const int* __restrict__ counts,
    unsigned* __restrict__ sgbits) {
  const int e = blockIdx.y;
  const int count = counts[e];
  const int s0 = blockIdx.x * 128;
  if (s0 >= count || count == 0) return;
  __shared__ float wsgS[2048 * 9];
  const int tid = threadIdx.x, lane = tid & 63, wid = tid >> 6;
  const float* wsg = w_sgate + (size_t)e * (HD * NSG);
#pragma unroll
  for (int p = 0; p < 8; ++p) {
    int row = p * 256 + tid;
    f32x4 v0 = *(const f32x4*)&wsg[row * 8];
    f32x4 v1 = *(const f32x4*)&wsg[row * 8 + 4];
#pragma unroll
    for (int c = 0; c < 4; ++c) {
      wsgS[row * 9 + c] = v0[c];
      wsgS[row * 9 + 4 + c] = v1[c];
    }
  }
  __syncthreads();
  const int base = s0 + wid * 32;
  for (int j = 0; j < 16; ++j) {
    int sA = base + j, sB = base + j + 16;
    if (sA >= count) break;
    int tokA = tok_idx[e * CAPE + sA];
    int tokB = tok_idx[e * CAPE + (sB < count ? sB : sA)];
    float zA[8], zB[8];
#pragma unroll
    for (int s = 0; s < 8; ++s) { zA[s] = 0.f; zB[s] = 0.f; }
    const float* rAp = rin + (size_t)tokA * HD;
    const float* rBp = rin + (size_t)tokB * HD;
#pragma unroll 4
    for (int i = 0; i < 32; ++i) {
      int h = lane + 64 * i;
      float rA = rAp[h];
      float rB = rBp[h];
#pragma unroll
      for (int s = 0; s < 8; ++s) {
        float w = wsgS[h * 9 + s];
        zA[s] += rA * w;
        zB[s] += rB * w;
      }
    }
#pragma unroll
    for (int s = 0; s < 8; ++s) {
#pragma unroll
      for (int d = 1; d < 64; d <<= 1) {
        zA[s] += __shfl_xor(zA[s], d);
        zB[s] += __shfl_xor(zB[s], d);
      }
    }
    if (lane == 0) {
      unsigned bA = 0, bB = 0;
#pragma unroll
      for (int s = 0; s < 8; ++s) {
        bA |= ((unsigned)(zA[s] > 0.f)) << s;
        bB |= ((unsigned)(zB[s] > 0.f)) << s;
      }
      sgbits[e * CAPE + sA] = bA;
      if (sB < count) sgbits[e * CAPE + sB] = bB;
    }
  }
}

// ---------------- prepass: x fp32 -> bf16 ----------------
__global__ __launch_bounds__(256) void cvt_x_kernel(const float* __restrict__ x,
                                                    unsigned short* __restrict__ xb) {
  size_t i = ((size_t)blockIdx.x * 256 + threadIdx.x) * 8;
  float4 a = *(const float4*)(x + i);
  float4 b = *(const float4*)(x + i + 4);
  us8 o = {f2bf(a.x), f2bf(a.y), f2bf(a.z), f2bf(a.w),
           f2bf(b.x), f2bf(b.y), f2bf(b.z), f2bf(b.w)};
  *(us8*)(xb + i) = o;
}

// ---------------- prepass: per-expert transpose+convert in[R][C] f32 -> out[C][R] bf16 ---
__global__ __launch_bounds__(256) void transpose_cvt_kernel(
    const float* __restrict__ in, unsigned short* __restrict__ out, int R, int C) {
  const int e = blockIdx.z;
  const int r0 = blockIdx.x * 64, c0 = blockIdx.y * 64;
  __shared__ float t[64][65];
  const int tid = threadIdx.x;
  const float* inp = in + (size_t)e * R * C;
  {
    const int row = tid >> 4, col4 = (tid & 15) << 2;
#pragma unroll
    for (int p = 0; p < 4; ++p) {
      float4 v = *(const float4*)(inp + (size_t)(r0 + p * 16 + row) * C + c0 + col4);
      t[p * 16 + row][col4 + 0] = v.x;
      t[p * 16 + row][col4 + 1] = v.y;
      t[p * 16 + row][col4 + 2] = v.z;
      t[p * 16 + row][col4 + 3] = v.w;
    }
  }
  __syncthreads();
  {
    const int c = tid >> 2, j = tid & 3;
    us8 o0, o1;
#pragma unroll
    for (int i = 0; i < 8; ++i) o0[i] = f2bf(t[j * 16 + i][c]);
#pragma unroll
    for (int i = 0; i < 8; ++i) o1[i] = f2bf(t[j * 16 + 8 + i][c]);
    unsigned short* op = out + (size_t)e * R * C + (size_t)(c0 + c) * R + r0 + j * 16;
    *(us8*)op = o0;
    *(us8*)(op + 8) = o1;
  }
}

// -------- up/gate GEMM: 128m x 64n, double-buffered LDS + counted vmcnt (T3/T4) --------
__global__ __launch_bounds__(256, 2) void up_gate_bf16(
    const unsigned short* __restrict__ xb, const unsigned short* __restrict__ wub,
    const unsigned short* __restrict__ wgb, const int* __restrict__ tok_idx,
    const int* __restrict__ counts, const unsigned* __restrict__ sgbits,
    const int* __restrict__ tlist, const int* __restrict__ ntiles,
    unsigned short* __restrict__ act) {
  const int hw = blockIdx.x;
  const int idx = (hw & 7) * (UPGRID / 8) + (hw >> 3);
  const int ti = idx / 12, nb = idx - ti * 12;
  if (ti >= ntiles[0]) return;
  const int entry = tlist[ti];
  const int e = entry >> 8;
  const int m0 = (entry & 255) << 7;
  const int n0 = nb * 64;
  const int count = counts[e];

  __shared__ __align__(16) unsigned short As0[128 * 64], As1[128 * 64];
  __shared__ __align__(16) unsigned short Bu0[64 * 64], Bu1[64 * 64];
  __shared__ __align__(16) unsigned short Bg0[64 * 64], Bg1[64 * 64];

  const int tid = threadIdx.x, lane = tid & 63, wid = tid >> 6;
  const int wr = wid >> 1, wc = wid & 1;
  const int ecap = e * CAPE;

  const int srow = tid >> 3, sblk = tid & 7;
  const unsigned short *gA[4], *gU[2], *gG[2];
#pragma unroll
  for (int c = 0; c < 4; ++c) {
    int r = c * 32 + srow;
    int gm = m0 + r;
    int gc = gm < count ? gm : count - 1;
    int swz = (sblk ^ (r & 7)) << 3;
    gA[c] = xb + (size_t)tok_idx[ecap + gc] * HD + swz;
  }
#pragma unroll
  for (int c = 0; c < 2; ++c) {
    int r = c * 32 + srow;
    int swz = (sblk ^ (r & 7)) << 3;
    gU[c] = wub + (size_t)(e * FD + n0 + r) * HD + swz;
    gG[c] = wgb + (size_t)(e * FD + n0 + r) * HD + swz;
  }

  f32x4 accU[4][2], accG[4][2];
#pragma unroll
  for (int i = 0; i < 4; ++i)
#pragma unroll
    for (int j = 0; j < 2; ++j) { accU[i][j] = (f32x4)0.f; accG[i][j] = (f32x4)0.f; }

  const int fr = lane & 15, fq = lane >> 4;
  const int frx = (fr & 7) << 3;
  const int toff = tid << 3;

  auto stage = [&](unsigned short* A_, unsigned short* U_, unsigned short* G_, int kt) {
#pragma unroll
    for (int c = 0; c < 4; ++c) async16(gA[c] + kt, A_ + toff + c * 2048);
#pragma unroll
    for (int c = 0; c < 2; ++c) {
      async16(gU[c] + kt, U_ + toff + c * 2048);
      async16(gG[c] + kt, G_ + toff + c * 2048);
    }
  };
  auto compute = [&](const unsigned short* A_, const unsigned short* U_,
                     const unsigned short* G_) {
#pragma unroll
    for (int kk = 0; kk < 64; kk += 32) {
      short8 af[4], bu[2], bg[2];
      const int kphys = (kk + fq * 8) ^ frx;
#pragma unroll
      for (int mi = 0; mi < 4; ++mi)
        af[mi] = *(const short8*)(A_ + ((wr * 64 + mi * 16 + fr) << 6) + kphys);
#pragma unroll
      for (int ni = 0; ni < 2; ++ni) {
        bu[ni] = *(const short8*)(U_ + ((wc * 32 + ni * 16 + fr) << 6) + kphys);
        bg[ni] = *(const short8*)(G_ + ((wc * 32 + ni * 16 + fr) << 6) + kphys);
      }
#pragma unroll
      for (int mi = 0; mi < 4; ++mi)
#pragma unroll
        for (int ni = 0; ni < 2; ++ni) {
          accU[mi][ni] = __builtin_amdgcn_mfma_f32_16x16x32_bf16(af[mi], bu[ni], accU[mi][ni], 0, 0, 0);
          accG[mi][ni] = __builtin_amdgcn_mfma_f32_16x16x32_bf16(af[mi], bg[ni], accG[mi][ni], 0, 0, 0);
        }
    }
  };

  stage(As0, Bu0, Bg0, 0);
  for (int kt = 0; kt < HD; kt += 128) {
    stage(As1, Bu1, Bg1, kt + 64);
    asm volatile("s_waitcnt vmcnt(8)" ::: "memory");
    __builtin_amdgcn_s_barrier();
    __builtin_amdgcn_sched_barrier(0);
    __builtin_amdgcn_s_setprio(1);
    compute(As0, Bu0, Bg0);
    __builtin_amdgcn_s_setprio(0);
    __builtin_amdgcn_sched_barrier(0);
    __builtin_amdgcn_s_barrier();
    if (kt + 128 < HD) {
      stage(As0, Bu0, Bg0, kt + 128);
      asm volatile("s_waitcnt vmcnt(8)" ::: "memory");
    } else {
      asm volatile("s_waitcnt vmcnt(0)" ::: "memory");
    }
    __builtin_amdgcn_s_barrier();
    __builtin_amdgcn_sched_barrier(0);
    __builtin_amdgcn_s_setprio(1);
    compute(As1, Bu1, Bg1);
    __builtin_amdgcn_s_setprio(0);
    __builtin_amdgcn_sched_barrier(0);
    __builtin_amdgcn_s_barrier();
  }

#pragma unroll
  for (int mi = 0; mi < 4; ++mi) {
#pragma unroll
    for (int q = 0; q < 4; ++q) {
      int grow = m0 + wr * 64 + mi * 16 + fq * 4 + q;
      if (grow < count) {
        unsigned sg = sgbits[ecap + grow];
        unsigned short* arow = act + (size_t)(ecap + grow) * FD + n0 + wc * 32 + fr;
#pragma unroll
        for (int ni = 0; ni < 2; ++ni) {
          int gcol = n0 + wc * 32 + ni * 16 + fr;
          float a = accU[mi][ni][q] * fmaxf(accG[mi][ni][q], 0.f);
          a = ((sg >> (gcol / 96)) & 1u) ? a : 0.f;
          arow[ni * 16] = f2bf(a);
        }
      }
    }
  }
}

// -------- down GEMM: double-buffered + counted vmcnt -> per-slot bf16 rows --------
__global__ __launch_bounds__(256, 2) void down_bf16(
    const unsigned short* __restrict__ act, const unsigned short* __restrict__ wdb,
    const int* __restrict__ counts, const int* __restrict__ tlist,
    const int* __restrict__ ntiles, unsigned short* __restrict__ act_dn) {
  const int hw = blockIdx.x;
  const int idx = (hw & 7) * (DNGRID / 8) + (hw >> 3);
  const int ti = idx >> 4, nb = idx & 15;
  if (ti >= ntiles[0]) return;
  const int entry = tlist[ti];
  const int e = entry >> 8;
  const int m0 = (entry & 255) << 7;
  const int n0 = nb * 128;
  const int count = counts[e];

  __shared__ __align__(16) unsigned short As0[128 * 64], As1[128 * 64];
  __shared__ __align__(16) unsigned short Bs0[128 * 64], Bs1[128 * 64];

  const int tid = threadIdx.x, lane = tid & 63, wid = tid >> 6;
  const int wr = wid >> 1, wc = wid & 1;
  const int ecap = e * CAPE;

  const int srow = tid >> 3, sblk = tid & 7;
  const unsigned short *gA[4], *gB[4];
#pragma unroll
  for (int c = 0; c < 4; ++c) {
    int r = c * 32 + srow;
    int gr = m0 + r;
    if (gr > CAPE - 1) gr = CAPE - 1;
    int swz = (sblk ^ (r & 7)) << 3;
    gA[c] = act + (size_t)(ecap + gr) * FD + swz;
    gB[c] = wdb + (size_t)(e * HD + n0 + r) * FD + swz;
  }

  f32x4 accD[4][4];
#pragma unroll
  for (int i = 0; i < 4; ++i)
#pragma unroll
    for (int j = 0; j < 4; ++j) accD[i][j] = (f32x4)0.f;

  const int fr = lane & 15, fq = lane >> 4;
  const int frx = (fr & 7) << 3;
  const int toff = tid << 3;

  auto stage = [&](unsigned short* A_, unsigned short* B_, int kt) {
#pragma unroll
    for (int c = 0; c < 4; ++c) {
      async16(gA[c] + kt, A_ + toff + c * 2048);
      async16(gB[c] + kt, B_ + toff + c * 2048);
    }
  };
  auto compute = [&](const unsigned short* A_, const unsigned short* B_) {
#pragma unroll
    for (int kk = 0; kk < 64; kk += 32) {
      short8 af[4], bb[4];
      const int kphys = (kk + fq * 8) ^ frx;
#pragma unroll
      for (int mi = 0; mi < 4; ++mi)
        af[mi] = *(const short8*)(A_ + ((wr * 64 + mi * 16 + fr) << 6) + kphys);
#pragma unroll
      for (int ni = 0; ni < 4; ++ni)
        bb[ni] = *(const short8*)(B_ + ((wc * 64 + ni * 16 + fr) << 6) + kphys);
#pragma unroll
      for (int mi = 0; mi < 4; ++mi)
#pragma unroll
        for (int ni = 0; ni < 4; ++ni)
          accD[mi][ni] = __builtin_amdgcn_mfma_f32_16x16x32_bf16(af[mi], bb[ni], accD[mi][ni], 0, 0, 0);
    }
  };

  stage(As0, Bs0, 0);
  for (int kt = 0; kt < FD; kt += 128) {
    stage(As1, Bs1, kt + 64);
    asm volatile("s_waitcnt vmcnt(8)" ::: "memory");
    __builtin_amdgcn_s_barrier();
    __builtin_amdgcn_sched_barrier(0);
    __builtin_amdgcn_s_setprio(1);
    compute(As0, Bs0);
    __builtin_amdgcn_s_setprio(0);
    __builtin_amdgcn_sched_barrier(0);
    __builtin_amdgcn_s_barrier();
    if (kt + 128 < FD) {
      stage(As0, Bs0, kt + 128);
      asm volatile("s_waitcnt vmcnt(8)" ::: "memory");
    } else {
      asm volatile("s_waitcnt vmcnt(0)" ::: "memory");
    }
    __builtin_amdgcn_s_barrier();
    __builtin_amdgcn_sched_barrier(0);
    __builtin_amdgcn_s_setprio(1);
    compute(As1, Bs1);
    __builtin_amdgcn_s_setprio(0);
    __builtin_amdgcn_sched_barrier(0);
    __builtin_amdgcn_s_barrier();
  }

#pragma unroll
  for (int mi = 0; mi < 4; ++mi) {
#pragma unroll
    for (int q = 0; q < 4; ++q) {
      int grow = m0 + wr * 64 + mi * 16 + fq * 4 + q;
      if (grow < count) {
        unsigned short* drow = act_dn + (size_t)(ecap + grow) * HD + n0 + wc * 64 + fr;
#pragma unroll
        for (int ni = 0; ni < 4; ++ni)
          drow[ni * 16] = f2bf(accD[mi][ni][q]);
      }
    }
  }
}

// ---------------- combine: out[t] = sum_k w[slot] * act_dn[slot] ----------------
__global__ __launch_bounds__(256) void combine_kernel(
    const unsigned short* __restrict__ act_dn, const float* __restrict__ tok_w,
    const int* __restrict__ slotmap, float* __restrict__ outF) {
  const int t = blockIdx.x;
  const int h = threadIdx.x * 8;
  const int4 sm = *(const int4*)(slotmap + t * TOPK);
  float acc[8];
#pragma unroll
  for (int j = 0; j < 8; ++j) acc[j] = 0.f;
  const int ss[4] = {sm.x, sm.y, sm.z, sm.w};
#pragma unroll
  for (int k = 0; k < TOPK; ++k) {
    int s = ss[k];
    if (s >= 0) {
      float w = tok_w[s];
      us8 v = *(const us8*)(act_dn + (size_t)s * HD + h);
#pragma unroll
      for (int j = 0; j < 8; ++j) acc[j] += w * bf2f(v[j]);
    }
  }
  float* op = outF + (size_t)t * HD + h;
  f32x4 o0 = {acc[0], acc[1], acc[2], acc[3]};
  f32x4 o1 = {acc[4], acc[5], acc[6], acc[7]};
  *(f32x4*)op = o0;
  *(f32x4*)(op + 4) = o1;
}

extern "C" void kernel_launch(void* const* d_in, const int* in_sizes, int n_in,
                              void* d_out, int out_size, void* d_ws, size_t ws_size,
                              hipStream_t stream) {
  const float* rin = (const float*)d_in[0];
  const float* x = (const float*)d_in[1];
  const float* w_router = (const float*)d_in[2];
  const float* w_up = (const float*)d_in[3];
  const float* w_gate = (const float*)d_in[4];
  const float* w_down = (const float*)d_in[5];
  const float* w_sg = (const float*)d_in[6];
  float* outF = (float*)d_out;
  float* top_logits = outF + (size_t)TT * HD;

  char* ws = (char*)d_ws;
  int* sel = (int*)(ws + 0);                      // 64 KB
  float* rwts = (float*)(ws + (64 << 10));        // 64 KB
  int* tidx = (int*)(ws + (192 << 10));           // 128 KB
  float* tw = (float*)(ws + (320 << 10));         // 128 KB
  unsigned* sgb = (unsigned*)(ws + (448 << 10));  // 128 KB
  int* counts = (int*)(ws + (576 << 10));
  int* tlist = (int*)(ws + (580 << 10));          // 1 KB
  int* ntiles = (int*)(ws + (584 << 10));
  int* slotmap = (int*)(ws + (1152 << 10));       // 64 KB
  unsigned short* act = (unsigned short*)(ws + ((size_t)2 << 20));   // 48 MB
  float* wrt = (float*)(ws + ((size_t)51 << 20));                    // 256 KB
  unsigned short* xb = (unsigned short*)(ws + ((size_t)52 << 20));   // 16 MB
  unsigned short* wub = (unsigned short*)(ws + ((size_t)69 << 20));  // 96 MB
  unsigned short* wgb = wub + (size_t)NE * HD * FD;                  // 96 MB
  unsigned short* wdb = wgb + (size_t)NE * HD * FD;                  // 96 MB
  unsigned short* act_dn = wub;  // overlays wub (dead once down_bf16 runs)

  // routing front-end
  wrt_kernel<<<256, 256, 0, stream>>>(w_router, wrt);
  logits_kernel<<<TT / 16, 256, 0, stream>>>(rin, wrt, top_logits, sel, rwts);
  dispatch_kernel<<<NE, 256, 0, stream>>>(sel, rwts, tidx, tw, counts, slotmap);
  build_tiles_kernel<<<1, 64, 0, stream>>>(counts, tlist, ntiles);
  sgate_kernel<<<dim3(CAPE / 128, NE), 256, 0, stream>>>(rin, w_sg, tidx, counts, sgb);

  // bf16 conversion prepasses
  cvt_x_kernel<<<(TT * HD) / (256 * 8), 256, 0, stream>>>(x, xb);
  transpose_cvt_kernel<<<dim3(HD / 64, FD / 64, NE), 256, 0, stream>>>(w_up, wub, HD, FD);
  transpose_cvt_kernel<<<dim3(HD / 64, FD / 64, NE), 256, 0, stream>>>(w_gate, wgb, HD, FD);
  transpose_cvt_kernel<<<dim3(FD / 64, HD / 64, NE), 256, 0, stream>>>(w_down, wdb, FD, HD);

  // expert GEMMs (work-list balanced, counted-vmcnt pipelined)
  up_gate_bf16<<<UPGRID, 256, 0, stream>>>(xb, wub, wgb, tidx, counts, sgb, tlist, ntiles, act);
  down_bf16<<<DNGRID, 256, 0, stream>>>(act, wdb, counts, tlist, ntiles, act_dn);
  combine_kernel<<<TT, 256, 0, stream>>>(act_dn, tw, slotmap, outF);
}

// Round 8
// 592.549 us; speedup vs baseline: 1.0403x; 1.0403x over previous
//
#include <hip/hip_runtime.h>

#define TT 4096
#define HD 2048
#define FD 768
#define NE 32
#define TOPK 4
#define NSG 8
#define CAPE 1024
#define MAXTILES 160
#define UPGRID (MAXTILES * 12)
#define DNGRID (MAXTILES * 16)

typedef __attribute__((ext_vector_type(8))) short short8;
typedef __attribute__((ext_vector_type(4))) float f32x4;
typedef __attribute__((ext_vector_type(4))) unsigned short us4;
typedef __attribute__((ext_vector_type(8))) unsigned short us8;

__device__ __forceinline__ unsigned short f2bf(float f) {
  unsigned u = __builtin_bit_cast(unsigned, f);
  u += 0x7FFFu + ((u >> 16) & 1u);
  return (unsigned short)(u >> 16);
}
__device__ __forceinline__ float bf2f(unsigned short b) {
  return __builtin_bit_cast(float, (unsigned)b << 16);
}

__device__ __forceinline__ void async16(const void* g, void* l) {
  __builtin_amdgcn_global_load_lds(
      (const __attribute__((address_space(1))) unsigned int*)g,
      (__attribute__((address_space(3))) unsigned int*)l, 16, 0, 0);
}

// ---------------- w_router [H][E] -> wrt [E][H] (fp32, tiny) ----------------
__global__ __launch_bounds__(256) void wrt_kernel(const float* __restrict__ w_router,
                                                  float* __restrict__ wrt) {
  int idx = blockIdx.x * 256 + threadIdx.x;
  int e = idx >> 11, h = idx & 2047;
  wrt[idx] = w_router[h * NE + e];
}

// -------- logits fp32 GEMM + fused top-4/softmax: [16 tok/block] x [32 experts] --------
#define LSTR 68
__global__ __launch_bounds__(256) void logits_kernel(
    const float* __restrict__ rin, const float* __restrict__ wrt,
    float* __restrict__ top_logits, int* __restrict__ sel, float* __restrict__ rwts) {
  __shared__ float As[16 * LSTR];
  __shared__ float Bs[32 * LSTR];
  __shared__ float lgS[16][33];
  const int tid = threadIdx.x;
  const int t0 = blockIdx.x * 16;
  const int tp = tid >> 4, eg = tid & 15;
  f32x4 acc0 = (f32x4)0.f, acc1 = (f32x4)0.f;
  for (int kt = 0; kt < HD; kt += 64) {
    __syncthreads();
    {
      int row = tid >> 4, col = (tid & 15) * 4;
      *(f32x4*)&As[row * LSTR + col] =
          *(const f32x4*)&rin[(size_t)(t0 + row) * HD + kt + col];
    }
    {
      int e = tid >> 3, col = (tid & 7) * 8;
      *(f32x4*)&Bs[e * LSTR + col] = *(const f32x4*)&wrt[(size_t)e * HD + kt + col];
      *(f32x4*)&Bs[e * LSTR + col + 4] =
          *(const f32x4*)&wrt[(size_t)e * HD + kt + col + 4];
    }
    __syncthreads();
#pragma unroll
    for (int k4 = 0; k4 < 16; ++k4) {
      f32x4 a = *(const f32x4*)&As[tp * LSTR + k4 * 4];
      f32x4 b0 = *(const f32x4*)&Bs[eg * LSTR + k4 * 4];
      f32x4 b1 = *(const f32x4*)&Bs[(eg + 16) * LSTR + k4 * 4];
      acc0 += a * b0;
      acc1 += a * b1;
    }
  }
  lgS[tp][eg] = acc0[0] + acc0[1] + acc0[2] + acc0[3];
  lgS[tp][eg + 16] = acc1[0] + acc1[1] + acc1[2] + acc1[3];
  __syncthreads();
  if (tid < 16) {
    const float* row = lgS[tid];
    float val[TOPK];
    int idx[TOPK];
    unsigned used = 0;
#pragma unroll
    for (int k = 0; k < TOPK; ++k) {
      float best = -1e30f;
      int bi = 0;
      for (int e = 0; e < NE; ++e) {
        float v = row[e];
        if (!((used >> e) & 1u) && v > best) { best = v; bi = e; }
      }
      used |= 1u << bi;
      val[k] = best;
      idx[k] = bi;
    }
    float ex[TOPK], sum = 0.f;
#pragma unroll
    for (int k = 0; k < TOPK; ++k) { ex[k] = expf(val[k] - val[0]); sum += ex[k]; }
    int t = t0 + tid;
#pragma unroll
    for (int k = 0; k < TOPK; ++k) {
      top_logits[t * TOPK + k] = val[k];
      sel[t * TOPK + k] = idx[k];
      rwts[t * TOPK + k] = ex[k] / sum;
    }
  }
}

// ---------------- dispatch: ordered compaction per expert + slot map ----------------
__global__ __launch_bounds__(256) void dispatch_kernel(
    const int* __restrict__ sel, const float* __restrict__ rwts,
    int* __restrict__ tok_idx, float* __restrict__ tok_w, int* __restrict__ counts,
    int* __restrict__ slotmap) {
  const int e = blockIdx.x;
  __shared__ int wcnt[4];
  __shared__ int base;
  const int tid = threadIdx.x, lane = tid & 63, wid = tid >> 6;
  if (tid == 0) base = 0;
  __syncthreads();
  for (int t0 = 0; t0 < TT; t0 += 256) {
    int t = t0 + tid;
    int hitk = -1;
#pragma unroll
    for (int k = 0; k < TOPK; ++k)
      if (sel[t * TOPK + k] == e) hitk = k;
    unsigned long long m = __ballot(hitk >= 0);
    if (lane == 0) wcnt[wid] = __popcll(m);
    __syncthreads();
    int off = base;
    for (int w = 0; w < wid; ++w) off += wcnt[w];
    int pos = off + __popcll(m & ((1ULL << lane) - 1ULL));
    if (hitk >= 0) {
      if (pos < CAPE) {
        tok_idx[e * CAPE + pos] = t;
        tok_w[e * CAPE + pos] = rwts[t * TOPK + hitk];
        slotmap[t * TOPK + hitk] = e * CAPE + pos;
      } else {
        slotmap[t * TOPK + hitk] = -1;
      }
    }
    __syncthreads();
    if (tid == 0) base += wcnt[0] + wcnt[1] + wcnt[2] + wcnt[3];
    __syncthreads();
  }
  if (tid == 0) counts[e] = base < CAPE ? base : CAPE;
}

// ---------------- tile work-list builder (deterministic order) ----------------
__global__ void build_tiles_kernel(const int* __restrict__ counts,
                                   int* __restrict__ tlist, int* __restrict__ ntiles) {
  if (threadIdx.x == 0) {
    int n = 0;
    for (int e = 0; e < NE; ++e) {
      int c = counts[e];
      int mb = (c + 127) >> 7;
      for (int m = 0; m < mb; ++m) tlist[n++] = (e << 8) | m;
    }
    ntiles[0] = n;
  }
}

// ---------------- secondary gate per (expert, slot) ----------------
__global__ __launch_bounds__(256) void sgate_kernel(
    const float* __restrict__ rin, const float* __restrict__ w_sgate,
    const int* __restrict__ tok_idx, const int* __restrict__ counts,
    unsigned* __restrict__ sgbits) {
  const int e = blockIdx.y;
  const int count = counts[e];
  const int s0 = blockIdx.x * 128;
  if (s0 >= count || count == 0) return;
  __shared__ float wsgS[2048 * 9];
  const int tid = threadIdx.x, lane = tid & 63, wid = tid >> 6;
  const float* wsg = w_sgate + (size_t)e * (HD * NSG);
#pragma unroll
  for (int p = 0; p < 8; ++p) {
    int row = p * 256 + tid;
    f32x4 v0 = *(const f32x4*)&wsg[row * 8];
    f32x4 v1 = *(const f32x4*)&wsg[row * 8 + 4];
#pragma unroll
    for (int c = 0; c < 4; ++c) {
      wsgS[row * 9 + c] = v0[c];
      wsgS[row * 9 + 4 + c] = v1[c];
    }
  }
  __syncthreads();
  const int base = s0 + wid * 32;
  for (int j = 0; j < 16; ++j) {
    int sA = base + j, sB = base + j + 16;
    if (sA >= count) break;
    int tokA = tok_idx[e * CAPE + sA];
    int tokB = tok_idx[e * CAPE + (sB < count ? sB : sA)];
    float zA[8], zB[8];
#pragma unroll
    for (int s = 0; s < 8; ++s) { zA[s] = 0.f; zB[s] = 0.f; }
    const float* rAp = rin + (size_t)tokA * HD;
    const float* rBp = rin + (size_t)tokB * HD;
#pragma unroll 4
    for (int i = 0; i < 32; ++i) {
      int h = lane + 64 * i;
      float rA = rAp[h];
      float rB = rBp[h];
#pragma unroll
      for (int s = 0; s < 8; ++s) {
        float w = wsgS[h * 9 + s];
        zA[s] += rA * w;
        zB[s] += rB * w;
      }
    }
#pragma unroll
    for (int s = 0; s < 8; ++s) {
#pragma unroll
      for (int d = 1; d < 64; d <<= 1) {
        zA[s] += __shfl_xor(zA[s], d);
        zB[s] += __shfl_xor(zB[s], d);
      }
    }
    if (lane == 0) {
      unsigned bA = 0, bB = 0;
#pragma unroll
      for (int s = 0; s < 8; ++s) {
        bA |= ((unsigned)(zA[s] > 0.f)) << s;
        bB |= ((unsigned)(zB[s] > 0.f)) << s;
      }
      sgbits[e * CAPE + sA] = bA;
      if (sB < count) sgbits[e * CAPE + sB] = bB;
    }
  }
}

// ---------------- prepass: x fp32 -> bf16 ----------------
__global__ __launch_bounds__(256) void cvt_x_kernel(const float* __restrict__ x,
                                                    unsigned short* __restrict__ xb) {
  size_t i = ((size_t)blockIdx.x * 256 + threadIdx.x) * 8;
  float4 a = *(const float4*)(x + i);
  float4 b = *(const float4*)(x + i + 4);
  us8 o = {f2bf(a.x), f2bf(a.y), f2bf(a.z), f2bf(a.w),
           f2bf(b.x), f2bf(b.y), f2bf(b.z), f2bf(b.w)};
  *(us8*)(xb + i) = o;
}

// ------- fused prepass: transpose+convert TWO matrices (up & gate) [R][C]->[C][R] -------
__global__ __launch_bounds__(256) void transpose_cvt2_kernel(
    const float* __restrict__ in1, const float* __restrict__ in2,
    unsigned short* __restrict__ out1, unsigned short* __restrict__ out2,
    int R, int C) {
  const int e = blockIdx.z;
  const int r0 = blockIdx.x * 64, c0 = blockIdx.y * 64;
  __shared__ float t[64][65];
  const int tid = threadIdx.x;
  const size_t ebase = (size_t)e * R * C;
#pragma unroll
  for (int m = 0; m < 2; ++m) {
    const float* inp = (m == 0 ? in1 : in2) + ebase;
    if (m) __syncthreads();
    {
      const int row = tid >> 4, col4 = (tid & 15) << 2;
#pragma unroll
      for (int p = 0; p < 4; ++p) {
        float4 v = *(const float4*)(inp + (size_t)(r0 + p * 16 + row) * C + c0 + col4);
        t[p * 16 + row][col4 + 0] = v.x;
        t[p * 16 + row][col4 + 1] = v.y;
        t[p * 16 + row][col4 + 2] = v.z;
        t[p * 16 + row][col4 + 3] = v.w;
      }
    }
    __syncthreads();
    {
      const int c = tid >> 2, j = tid & 3;
      us8 o0, o1;
#pragma unroll
      for (int i = 0; i < 8; ++i) o0[i] = f2bf(t[j * 16 + i][c]);
#pragma unroll
      for (int i = 0; i < 8; ++i) o1[i] = f2bf(t[j * 16 + 8 + i][c]);
      unsigned short* op =
          (m == 0 ? out1 : out2) + ebase + (size_t)(c0 + c) * R + r0 + j * 16;
      *(us8*)op = o0;
      *(us8*)(op + 8) = o1;
    }
  }
}

// ---------------- prepass: single transpose+convert (w_down) ----------------
__global__ __launch_bounds__(256) void transpose_cvt_kernel(
    const float* __restrict__ in, unsigned short* __restrict__ out, int R, int C) {
  const int e = blockIdx.z;
  const int r0 = blockIdx.x * 64, c0 = blockIdx.y * 64;
  __shared__ float t[64][65];
  const int tid = threadIdx.x;
  const float* inp = in + (size_t)e * R * C;
  {
    const int row = tid >> 4, col4 = (tid & 15) << 2;
#pragma unroll
    for (int p = 0; p < 4; ++p) {
      float4 v = *(const float4*)(inp + (size_t)(r0 + p * 16 + row) * C + c0 + col4);
      t[p * 16 + row][col4 + 0] = v.x;
      t[p * 16 + row][col4 + 1] = v.y;
      t[p * 16 + row][col4 + 2] = v.z;
      t[p * 16 + row][col4 + 3] = v.w;
    }
  }
  __syncthreads();
  {
    const int c = tid >> 2, j = tid & 3;
    us8 o0, o1;
#pragma unroll
    for (int i = 0; i < 8; ++i) o0[i] = f2bf(t[j * 16 + i][c]);
#pragma unroll
    for (int i = 0; i < 8; ++i) o1[i] = f2bf(t[j * 16 + 8 + i][c]);
    unsigned short* op = out + (size_t)e * R * C + (size_t)(c0 + c) * R + r0 + j * 16;
    *(us8*)op = o0;
    *(us8*)(op + 8) = o1;
  }
}

// ---------------- up/gate GEMM: 128m x 64n, single-buffer (proven round-6 form) --------
__global__ __launch_bounds__(256, 3) void up_gate_bf16(
    const unsigned short* __restrict__ xb, const unsigned short* __restrict__ wub,
    const unsigned short* __restrict__ wgb, const int* __restrict__ tok_idx,
    const int* __restrict__ counts, const unsigned* __restrict__ sgbits,
    const int* __restrict__ tlist, const int* __restrict__ ntiles,
    unsigned short* __restrict__ act) {
  const int hw = blockIdx.x;
  const int idx = (hw & 7) * (UPGRID / 8) + (hw >> 3);
  const int ti = idx / 12, nb = idx - ti * 12;
  if (ti >= ntiles[0]) return;
  const int entry = tlist[ti];
  const int e = entry >> 8;
  const int m0 = (entry & 255) << 7;
  const int n0 = nb * 64;
  const int count = counts[e];

  __shared__ __align__(16) unsigned short As[128 * 64];
  __shared__ __align__(16) unsigned short Bu[64 * 64];
  __shared__ __align__(16) unsigned short Bg[64 * 64];

  const int tid = threadIdx.x, lane = tid & 63, wid = tid >> 6;
  const int wr = wid >> 1, wc = wid & 1;
  const int ecap = e * CAPE;

  const int srow = tid >> 3, sblk = tid & 7;
  const unsigned short *gA[4], *gU[2], *gG[2];
#pragma unroll
  for (int c = 0; c < 4; ++c) {
    int r = c * 32 + srow;
    int gm = m0 + r;
    int gc = gm < count ? gm : count - 1;
    int swz = (sblk ^ (r & 7)) << 3;
    gA[c] = xb + (size_t)tok_idx[ecap + gc] * HD + swz;
  }
#pragma unroll
  for (int c = 0; c < 2; ++c) {
    int r = c * 32 + srow;
    int swz = (sblk ^ (r & 7)) << 3;
    gU[c] = wub + (size_t)(e * FD + n0 + r) * HD + swz;
    gG[c] = wgb + (size_t)(e * FD + n0 + r) * HD + swz;
  }
  unsigned short* lA = As + (tid << 3);
  unsigned short* lU = Bu + (tid << 3);
  unsigned short* lG = Bg + (tid << 3);

  f32x4 accU[4][2], accG[4][2];
#pragma unroll
  for (int i = 0; i < 4; ++i)
#pragma unroll
    for (int j = 0; j < 2; ++j) { accU[i][j] = (f32x4)0.f; accG[i][j] = (f32x4)0.f; }

  const int fr = lane & 15, fq = lane >> 4;
  const int frx = (fr & 7) << 3;

  for (int kt = 0; kt < HD; kt += 64) {
    __syncthreads();
#pragma unroll
    for (int c = 0; c < 4; ++c) async16(gA[c] + kt, lA + c * 2048);
#pragma unroll
    for (int c = 0; c < 2; ++c) {
      async16(gU[c] + kt, lU + c * 2048);
      async16(gG[c] + kt, lG + c * 2048);
    }
    __syncthreads();
#pragma unroll
    for (int kk = 0; kk < 64; kk += 32) {
      short8 af[4], bu[2], bg[2];
      const int kphys = (kk + fq * 8) ^ frx;
#pragma unroll
      for (int mi = 0; mi < 4; ++mi)
        af[mi] = *(const short8*)(As + ((wr * 64 + mi * 16 + fr) << 6) + kphys);
#pragma unroll
      for (int ni = 0; ni < 2; ++ni) {
        bu[ni] = *(const short8*)(Bu + ((wc * 32 + ni * 16 + fr) << 6) + kphys);
        bg[ni] = *(const short8*)(Bg + ((wc * 32 + ni * 16 + fr) << 6) + kphys);
      }
#pragma unroll
      for (int mi = 0; mi < 4; ++mi)
#pragma unroll
        for (int ni = 0; ni < 2; ++ni) {
          accU[mi][ni] = __builtin_amdgcn_mfma_f32_16x16x32_bf16(af[mi], bu[ni], accU[mi][ni], 0, 0, 0);
          accG[mi][ni] = __builtin_amdgcn_mfma_f32_16x16x32_bf16(af[mi], bg[ni], accG[mi][ni], 0, 0, 0);
        }
    }
  }
#pragma unroll
  for (int mi = 0; mi < 4; ++mi) {
#pragma unroll
    for (int q = 0; q < 4; ++q) {
      int grow = m0 + wr * 64 + mi * 16 + fq * 4 + q;
      if (grow < count) {
        unsigned sg = sgbits[ecap + grow];
        unsigned short* arow = act + (size_t)(ecap + grow) * FD + n0 + wc * 32 + fr;
#pragma unroll
        for (int ni = 0; ni < 2; ++ni) {
          int gcol = n0 + wc * 32 + ni * 16 + fr;
          float a = accU[mi][ni][q] * fmaxf(accG[mi][ni][q], 0.f);
          a = ((sg >> (gcol / 96)) & 1u) ? a : 0.f;
          arow[ni * 16] = f2bf(a);
        }
      }
    }
  }
}

// ---------------- down GEMM (single-buffer, round-6 form) -> per-slot bf16 rows --------
__global__ __launch_bounds__(256, 3) void down_bf16(
    const unsigned short* __restrict__ act, const unsigned short* __restrict__ wdb,
    const int* __restrict__ counts, const int* __restrict__ tlist,
    const int* __restrict__ ntiles, unsigned short* __restrict__ act_dn) {
  const int hw = blockIdx.x;
  const int idx = (hw & 7) * (DNGRID / 8) + (hw >> 3);
  const int ti = idx >> 4, nb = idx & 15;
  if (ti >= ntiles[0]) return;
  const int entry = tlist[ti];
  const int e = entry >> 8;
  const int m0 = (entry & 255) << 7;
  const int n0 = nb * 128;
  const int count = counts[e];

  __shared__ __align__(16) unsigned short As[128 * 64];
  __shared__ __align__(16) unsigned short Bs[128 * 64];

  const int tid = threadIdx.x, lane = tid & 63, wid = tid >> 6;
  const int wr = wid >> 1, wc = wid & 1;
  const int ecap = e * CAPE;

  const int srow = tid >> 3, sblk = tid & 7;
  const unsigned short *gA[4], *gB[4];
#pragma unroll
  for (int c = 0; c < 4; ++c) {
    int r = c * 32 + srow;
    int gr = m0 + r;
    if (gr > CAPE - 1) gr = CAPE - 1;
    int swz = (sblk ^ (r & 7)) << 3;
    gA[c] = act + (size_t)(ecap + gr) * FD + swz;
    gB[c] = wdb + (size_t)(e * HD + n0 + r) * FD + swz;
  }
  unsigned short* lA = As + (tid << 3);
  unsigned short* lB = Bs + (tid << 3);

  f32x4 accD[4][4];
#pragma unroll
  for (int i = 0; i < 4; ++i)
#pragma unroll
    for (int j = 0; j < 4; ++j) accD[i][j] = (f32x4)0.f;

  const int fr = lane & 15, fq = lane >> 4;
  const int frx = (fr & 7) << 3;

  for (int kt = 0; kt < FD; kt += 64) {
    __syncthreads();
#pragma unroll
    for (int c = 0; c < 4; ++c) {
      async16(gA[c] + kt, lA + c * 2048);
      async16(gB[c] + kt, lB + c * 2048);
    }
    __syncthreads();
#pragma unroll
    for (int kk = 0; kk < 64; kk += 32) {
      short8 af[4], bb[4];
      const int kphys = (kk + fq * 8) ^ frx;
#pragma unroll
      for (int mi = 0; mi < 4; ++mi)
        af[mi] = *(const short8*)(As + ((wr * 64 + mi * 16 + fr) << 6) + kphys);
#pragma unroll
      for (int ni = 0; ni < 4; ++ni)
        bb[ni] = *(const short8*)(Bs + ((wc * 64 + ni * 16 + fr) << 6) + kphys);
#pragma unroll
      for (int mi = 0; mi < 4; ++mi)
#pragma unroll
        for (int ni = 0; ni < 4; ++ni)
          accD[mi][ni] = __builtin_amdgcn_mfma_f32_16x16x32_bf16(af[mi], bb[ni], accD[mi][ni], 0, 0, 0);
    }
  }
#pragma unroll
  for (int mi = 0; mi < 4; ++mi) {
#pragma unroll
    for (int q = 0; q < 4; ++q) {
      int grow = m0 + wr * 64 + mi * 16 + fq * 4 + q;
      if (grow < count) {
        unsigned short* drow = act_dn + (size_t)(ecap + grow) * HD + n0 + wc * 64 + fr;
#pragma unroll
        for (int ni = 0; ni < 4; ++ni)
          drow[ni * 16] = f2bf(accD[mi][ni][q]);
      }
    }
  }
}

// ---------------- combine: out[t] = sum_k w[slot] * act_dn[slot] ----------------
__global__ __launch_bounds__(256) void combine_kernel(
    const unsigned short* __restrict__ act_dn, const float* __restrict__ tok_w,
    const int* __restrict__ slotmap, float* __restrict__ outF) {
  const int t = blockIdx.x;
  const int h = threadIdx.x * 8;
  const int4 sm = *(const int4*)(slotmap + t * TOPK);
  float acc[8];
#pragma unroll
  for (int j = 0; j < 8; ++j) acc[j] = 0.f;
  const int ss[4] = {sm.x, sm.y, sm.z, sm.w};
#pragma unroll
  for (int k = 0; k < TOPK; ++k) {
    int s = ss[k];
    if (s >= 0) {
      float w = tok_w[s];
      us8 v = *(const us8*)(act_dn + (size_t)s * HD + h);
#pragma unroll
      for (int j = 0; j < 8; ++j) acc[j] += w * bf2f(v[j]);
    }
  }
  float* op = outF + (size_t)t * HD + h;
  f32x4 o0 = {acc[0], acc[1], acc[2], acc[3]};
  f32x4 o1 = {acc[4], acc[5], acc[6], acc[7]};
  *(f32x4*)op = o0;
  *(f32x4*)(op + 4) = o1;
}

extern "C" void kernel_launch(void* const* d_in, const int* in_sizes, int n_in,
                              void* d_out, int out_size, void* d_ws, size_t ws_size,
                              hipStream_t stream) {
  const float* rin = (const float*)d_in[0];
  const float* x = (const float*)d_in[1];
  const float* w_router = (const float*)d_in[2];
  const float* w_up = (const float*)d_in[3];
  const float* w_gate = (const float*)d_in[4];
  const float* w_down = (const float*)d_in[5];
  const float* w_sg = (const float*)d_in[6];
  float* outF = (float*)d_out;
  float* top_logits = outF + (size_t)TT * HD;

  char* ws = (char*)d_ws;
  int* sel = (int*)(ws + 0);                      // 64 KB
  float* rwts = (float*)(ws + (64 << 10));        // 64 KB
  int* tidx = (int*)(ws + (192 << 10));           // 128 KB
  float* tw = (float*)(ws + (320 << 10));         // 128 KB
  unsigned* sgb = (unsigned*)(ws + (448 << 10));  // 128 KB
  int* counts = (int*)(ws + (576 << 10));
  int* tlist = (int*)(ws + (580 << 10));          // 1 KB
  int* ntiles = (int*)(ws + (584 << 10));
  int* slotmap = (int*)(ws + (1152 << 10));       // 64 KB
  unsigned short* act = (unsigned short*)(ws + ((size_t)2 << 20));   // 48 MB
  float* wrt = (float*)(ws + ((size_t)51 << 20));                    // 256 KB
  unsigned short* xb = (unsigned short*)(ws + ((size_t)52 << 20));   // 16 MB
  unsigned short* wub = (unsigned short*)(ws + ((size_t)69 << 20));  // 96 MB
  unsigned short* wgb = wub + (size_t)NE * HD * FD;                  // 96 MB
  unsigned short* wdb = wgb + (size_t)NE * HD * FD;                  // 96 MB
  unsigned short* act_dn = wub;  // overlays wub+wgb (dead once down_bf16 runs), 128 MB

  // routing front-end
  wrt_kernel<<<256, 256, 0, stream>>>(w_router, wrt);
  logits_kernel<<<TT / 16, 256, 0, stream>>>(rin, wrt, top_logits, sel, rwts);
  dispatch_kernel<<<NE, 256, 0, stream>>>(sel, rwts, tidx, tw, counts, slotmap);
  build_tiles_kernel<<<1, 64, 0, stream>>>(counts, tlist, ntiles);
  sgate_kernel<<<dim3(CAPE / 128, NE), 256, 0, stream>>>(rin, w_sg, tidx, counts, sgb);

  // bf16 conversion prepasses (up+gate fused)
  cvt_x_kernel<<<(TT * HD) / (256 * 8), 256, 0, stream>>>(x, xb);
  transpose_cvt2_kernel<<<dim3(HD / 64, FD / 64, NE), 256, 0, stream>>>(w_up, w_gate, wub, wgb, HD, FD);
  transpose_cvt_kernel<<<dim3(FD / 64, HD / 64, NE), 256, 0, stream>>>(w_down, wdb, FD, HD);

  // expert GEMMs (work-list balanced)
  up_gate_bf16<<<UPGRID, 256, 0, stream>>>(xb, wub, wgb, tidx, counts, sgb, tlist, ntiles, act);
  down_bf16<<<DNGRID, 256, 0, stream>>>(act, wdb, counts, tlist, ntiles, act_dn);
  combine_kernel<<<TT, 256, 0, stream>>>(act_dn, tw, slotmap, outF);
}

// Round 9
// 583.088 us; speedup vs baseline: 1.0572x; 1.0162x over previous
//
#include <hip/hip_runtime.h>

#define TT 4096
#define HD 2048
#define FD 768
#define NE 32
#define TOPK 4
#define NSG 8
#define CAPE 1024
#define MAXTILES 160
#define UPGRID (MAXTILES * 12)
#define DNGRID (MAXTILES * 16)

typedef __attribute__((ext_vector_type(8))) short short8;
typedef __attribute__((ext_vector_type(4))) float f32x4;
typedef __attribute__((ext_vector_type(4))) unsigned short us4;
typedef __attribute__((ext_vector_type(8))) unsigned short us8;

__device__ __forceinline__ unsigned short f2bf(float f) {
  unsigned u = __builtin_bit_cast(unsigned, f);
  u += 0x7FFFu + ((u >> 16) & 1u);
  return (unsigned short)(u >> 16);
}
__device__ __forceinline__ float bf2f(unsigned short b) {
  return __builtin_bit_cast(float, (unsigned)b << 16);
}

__device__ __forceinline__ void async16(const void* g, void* l) {
  __builtin_amdgcn_global_load_lds(
      (const __attribute__((address_space(1))) unsigned int*)g,
      (__attribute__((address_space(3))) unsigned int*)l, 16, 0, 0);
}

// derive (e, m0, count) for linear tile index ti, walking counts in expert order
// (identical deterministic order to the old build_tiles worklist). Returns e<0 if
// ti is past the last tile.
__device__ __forceinline__ void tile_from_counts(const int* __restrict__ counts,
                                                 int ti, int& e, int& m0, int& count) {
  e = -1;
  m0 = 0;
  count = 0;
  int acc = 0;
  for (int ee = 0; ee < NE; ++ee) {
    int c = counts[ee];
    int mb = (c + 127) >> 7;
    if (e < 0 && ti < acc + mb) {
      e = ee;
      m0 = (ti - acc) << 7;
      count = c;
    }
    acc += mb;
  }
}

// -------- logits fp32 GEMM + fused top-4/softmax; w_router read natively (no wrt) ------
#define LSTR 68
__global__ __launch_bounds__(256) void logits_kernel(
    const float* __restrict__ rin, const float* __restrict__ w_router,
    float* __restrict__ top_logits, int* __restrict__ sel, float* __restrict__ rwts) {
  __shared__ float As[16 * LSTR];
  __shared__ float Bs[32 * LSTR];
  __shared__ float lgS[16][33];
  const int tid = threadIdx.x;
  const int t0 = blockIdx.x * 16;
  const int tp = tid >> 4, eg = tid & 15;
  f32x4 acc0 = (f32x4)0.f, acc1 = (f32x4)0.f;
  for (int kt = 0; kt < HD; kt += 64) {
    __syncthreads();
    {  // stage A: 16 x 64 floats (4 rows x 256B per wave)
      int row = tid >> 4, col = (tid & 15) * 4;
      *(f32x4*)&As[row * LSTR + col] =
          *(const f32x4*)&rin[(size_t)(t0 + row) * HD + kt + col];
    }
    {  // stage B transposed from native w_router[h][e]: wave = 16 rows x 128B
      int hh = tid >> 2, eq = tid & 3;
      const float* wr = &w_router[(size_t)(kt + hh) * NE + eq * 8];
      f32x4 v0 = *(const f32x4*)wr;
      f32x4 v1 = *(const f32x4*)(wr + 4);
#pragma unroll
      for (int c2 = 0; c2 < 4; ++c2) {
        Bs[(eq * 8 + c2) * LSTR + hh] = v0[c2];
        Bs[(eq * 8 + 4 + c2) * LSTR + hh] = v1[c2];
      }
    }
    __syncthreads();
#pragma unroll
    for (int k4 = 0; k4 < 16; ++k4) {
      f32x4 a = *(const f32x4*)&As[tp * LSTR + k4 * 4];
      f32x4 b0 = *(const f32x4*)&Bs[eg * LSTR + k4 * 4];
      f32x4 b1 = *(const f32x4*)&Bs[(eg + 16) * LSTR + k4 * 4];
      acc0 += a * b0;
      acc1 += a * b1;
    }
  }
  lgS[tp][eg] = acc0[0] + acc0[1] + acc0[2] + acc0[3];
  lgS[tp][eg + 16] = acc1[0] + acc1[1] + acc1[2] + acc1[3];
  __syncthreads();
  if (tid < 16) {
    const float* row = lgS[tid];
    float val[TOPK];
    int idx[TOPK];
    unsigned used = 0;
#pragma unroll
    for (int k = 0; k < TOPK; ++k) {
      float best = -1e30f;
      int bi = 0;
      for (int e = 0; e < NE; ++e) {
        float v = row[e];
        if (!((used >> e) & 1u) && v > best) { best = v; bi = e; }
      }
      used |= 1u << bi;
      val[k] = best;
      idx[k] = bi;
    }
    float ex[TOPK], sum = 0.f;
#pragma unroll
    for (int k = 0; k < TOPK; ++k) { ex[k] = expf(val[k] - val[0]); sum += ex[k]; }
    int t = t0 + tid;
#pragma unroll
    for (int k = 0; k < TOPK; ++k) {
      top_logits[t * TOPK + k] = val[k];
      sel[t * TOPK + k] = idx[k];
      rwts[t * TOPK + k] = ex[k] / sum;
    }
  }
}

// ---------------- dispatch: ordered compaction per expert + slot map ----------------
__global__ __launch_bounds__(256) void dispatch_kernel(
    const int* __restrict__ sel, const float* __restrict__ rwts,
    int* __restrict__ tok_idx, float* __restrict__ tok_w, int* __restrict__ counts,
    int* __restrict__ slotmap) {
  const int e = blockIdx.x;
  __shared__ int wcnt[4];
  __shared__ int base;
  const int tid = threadIdx.x, lane = tid & 63, wid = tid >> 6;
  if (tid == 0) base = 0;
  __syncthreads();
  for (int t0 = 0; t0 < TT; t0 += 256) {
    int t = t0 + tid;
    int hitk = -1;
#pragma unroll
    for (int k = 0; k < TOPK; ++k)
      if (sel[t * TOPK + k] == e) hitk = k;
    unsigned long long m = __ballot(hitk >= 0);
    if (lane == 0) wcnt[wid] = __popcll(m);
    __syncthreads();
    int off = base;
    for (int w = 0; w < wid; ++w) off += wcnt[w];
    int pos = off + __popcll(m & ((1ULL << lane) - 1ULL));
    if (hitk >= 0) {
      if (pos < CAPE) {
        tok_idx[e * CAPE + pos] = t;
        tok_w[e * CAPE + pos] = rwts[t * TOPK + hitk];
        slotmap[t * TOPK + hitk] = e * CAPE + pos;
      } else {
        slotmap[t * TOPK + hitk] = -1;
      }
    }
    __syncthreads();
    if (tid == 0) base += wcnt[0] + wcnt[1] + wcnt[2] + wcnt[3];
    __syncthreads();
  }
  if (tid == 0) counts[e] = base < CAPE ? base : CAPE;
}

// ---------------- secondary gate per (expert, slot) ----------------
__global__ __launch_bounds__(256) void sgate_kernel(
    const float* __restrict__ rin, const float* __restrict__ w_sgate,
    const int* __restrict__ tok_idx, const int* __restrict__ counts,
    unsigned* __restrict__ sgbits) {
  const int e = blockIdx.y;
  const int count = counts[e];
  const int s0 = blockIdx.x * 128;
  if (s0 >= count || count == 0) return;
  __shared__ float wsgS[2048 * 9];
  const int tid = threadIdx.x, lane = tid & 63, wid = tid >> 6;
  const float* wsg = w_sgate + (size_t)e * (HD * NSG);
#pragma unroll
  for (int p = 0; p < 8; ++p) {
    int row = p * 256 + tid;
    f32x4 v0 = *(const f32x4*)&wsg[row * 8];
    f32x4 v1 = *(const f32x4*)&wsg[row * 8 + 4];
#pragma unroll
    for (int c = 0; c < 4; ++c) {
      wsgS[row * 9 + c] = v0[c];
      wsgS[row * 9 + 4 + c] = v1[c];
    }
  }
  __syncthreads();
  const int base = s0 + wid * 32;
  for (int j = 0; j < 16; ++j) {
    int sA = base + j, sB = base + j + 16;
    if (sA >= count) break;
    int tokA = tok_idx[e * CAPE + sA];
    int tokB = tok_idx[e * CAPE + (sB < count ? sB : sA)];
    float zA[8], zB[8];
#pragma unroll
    for (int s = 0; s < 8; ++s) { zA[s] = 0.f; zB[s] = 0.f; }
    const float* rAp = rin + (size_t)tokA * HD;
    const float* rBp = rin + (size_t)tokB * HD;
#pragma unroll 4
    for (int i = 0; i < 32; ++i) {
      int h = lane + 64 * i;
      float rA = rAp[h];
      float rB = rBp[h];
#pragma unroll
      for (int s = 0; s < 8; ++s) {
        float w = wsgS[h * 9 + s];
        zA[s] += rA * w;
        zB[s] += rB * w;
      }
    }
#pragma unroll
    for (int s = 0; s < 8; ++s) {
#pragma unroll
      for (int d = 1; d < 64; d <<= 1) {
        zA[s] += __shfl_xor(zA[s], d);
        zB[s] += __shfl_xor(zB[s], d);
      }
    }
    if (lane == 0) {
      unsigned bA = 0, bB = 0;
#pragma unroll
      for (int s = 0; s < 8; ++s) {
        bA |= ((unsigned)(zA[s] > 0.f)) << s;
        bB |= ((unsigned)(zB[s] > 0.f)) << s;
      }
      sgbits[e * CAPE + sA] = bA;
      if (sB < count) sgbits[e * CAPE + sB] = bB;
    }
  }
}

// ---------------- prepass: x fp32 -> bf16 ----------------
__global__ __launch_bounds__(256) void cvt_x_kernel(const float* __restrict__ x,
                                                    unsigned short* __restrict__ xb) {
  size_t i = ((size_t)blockIdx.x * 256 + threadIdx.x) * 8;
  float4 a = *(const float4*)(x + i);
  float4 b = *(const float4*)(x + i + 4);
  us8 o = {f2bf(a.x), f2bf(a.y), f2bf(a.z), f2bf(a.w),
           f2bf(b.x), f2bf(b.y), f2bf(b.z), f2bf(b.w)};
  *(us8*)(xb + i) = o;
}

// ------- fused prepass: transpose+convert TWO matrices; 128B-coalesced writes ---------
__global__ __launch_bounds__(256) void transpose_cvt2_kernel(
    const float* __restrict__ in1, const float* __restrict__ in2,
    unsigned short* __restrict__ out1, unsigned short* __restrict__ out2,
    int R, int C) {
  const int e = blockIdx.z;
  const int r0 = blockIdx.x * 64, c0 = blockIdx.y * 64;
  __shared__ float t[64][65];
  const int tid = threadIdx.x;
  const size_t ebase = (size_t)e * R * C;
#pragma unroll
  for (int m = 0; m < 2; ++m) {
    const float* inp = (m == 0 ? in1 : in2) + ebase;
    if (m) __syncthreads();
    {  // reads: wave = 4 rows x 256B
      const int row = tid >> 4, col4 = (tid & 15) << 2;
#pragma unroll
      for (int p = 0; p < 4; ++p) {
        float4 v = *(const float4*)(inp + (size_t)(r0 + p * 16 + row) * C + c0 + col4);
        t[p * 16 + row][col4 + 0] = v.x;
        t[p * 16 + row][col4 + 1] = v.y;
        t[p * 16 + row][col4 + 2] = v.z;
        t[p * 16 + row][col4 + 3] = v.w;
      }
    }
    __syncthreads();
    {  // writes: 8 threads cover a full 128B output row => wave = 8 rows x 128B
      const int c = tid >> 3, j = tid & 7;
      unsigned short* outp = (m == 0 ? out1 : out2) + ebase;
#pragma unroll
      for (int half = 0; half < 2; ++half) {
        int cc = c + half * 32;
        us8 o;
#pragma unroll
        for (int i = 0; i < 8; ++i) o[i] = f2bf(t[j * 8 + i][cc]);
        *(us8*)(outp + (size_t)(c0 + cc) * R + r0 + j * 8) = o;
      }
    }
  }
}

// ---------------- prepass: single transpose+convert (w_down), same write fix ----------
__global__ __launch_bounds__(256) void transpose_cvt_kernel(
    const float* __restrict__ in, unsigned short* __restrict__ out, int R, int C) {
  const int e = blockIdx.z;
  const int r0 = blockIdx.x * 64, c0 = blockIdx.y * 64;
  __shared__ float t[64][65];
  const int tid = threadIdx.x;
  const float* inp = in + (size_t)e * R * C;
  {
    const int row = tid >> 4, col4 = (tid & 15) << 2;
#pragma unroll
    for (int p = 0; p < 4; ++p) {
      float4 v = *(const float4*)(inp + (size_t)(r0 + p * 16 + row) * C + c0 + col4);
      t[p * 16 + row][col4 + 0] = v.x;
      t[p * 16 + row][col4 + 1] = v.y;
      t[p * 16 + row][col4 + 2] = v.z;
      t[p * 16 + row][col4 + 3] = v.w;
    }
  }
  __syncthreads();
  {
    const int c = tid >> 3, j = tid & 7;
    unsigned short* outp = out + (size_t)e * R * C;
#pragma unroll
    for (int half = 0; half < 2; ++half) {
      int cc = c + half * 32;
      us8 o;
#pragma unroll
      for (int i = 0; i < 8; ++i) o[i] = f2bf(t[j * 8 + i][cc]);
      *(us8*)(outp + (size_t)(c0 + cc) * R + r0 + j * 8) = o;
    }
  }
}

// ---------------- up/gate GEMM: 128m x 64n, single-buffer (proven round-6 form) --------
__global__ __launch_bounds__(256, 3) void up_gate_bf16(
    const unsigned short* __restrict__ xb, const unsigned short* __restrict__ wub,
    const unsigned short* __restrict__ wgb, const int* __restrict__ tok_idx,
    const int* __restrict__ counts, const unsigned* __restrict__ sgbits,
    unsigned short* __restrict__ act) {
  const int hw = blockIdx.x;
  const int idx = (hw & 7) * (UPGRID / 8) + (hw >> 3);
  const int ti = idx / 12, nb = idx - ti * 12;
  int e, m0, count;
  tile_from_counts(counts, ti, e, m0, count);
  if (e < 0) return;
  const int n0 = nb * 64;

  __shared__ __align__(16) unsigned short As[128 * 64];
  __shared__ __align__(16) unsigned short Bu[64 * 64];
  __shared__ __align__(16) unsigned short Bg[64 * 64];

  const int tid = threadIdx.x, lane = tid & 63, wid = tid >> 6;
  const int wr = wid >> 1, wc = wid & 1;
  const int ecap = e * CAPE;

  const int srow = tid >> 3, sblk = tid & 7;
  const unsigned short *gA[4], *gU[2], *gG[2];
#pragma unroll
  for (int c = 0; c < 4; ++c) {
    int r = c * 32 + srow;
    int gm = m0 + r;
    int gc = gm < count ? gm : count - 1;
    int swz = (sblk ^ (r & 7)) << 3;
    gA[c] = xb + (size_t)tok_idx[ecap + gc] * HD + swz;
  }
#pragma unroll
  for (int c = 0; c < 2; ++c) {
    int r = c * 32 + srow;
    int swz = (sblk ^ (r & 7)) << 3;
    gU[c] = wub + (size_t)(e * FD + n0 + r) * HD + swz;
    gG[c] = wgb + (size_t)(e * FD + n0 + r) * HD + swz;
  }
  unsigned short* lA = As + (tid << 3);
  unsigned short* lU = Bu + (tid << 3);
  unsigned short* lG = Bg + (tid << 3);

  f32x4 accU[4][2], accG[4][2];
#pragma unroll
  for (int i = 0; i < 4; ++i)
#pragma unroll
    for (int j = 0; j < 2; ++j) { accU[i][j] = (f32x4)0.f; accG[i][j] = (f32x4)0.f; }

  const int fr = lane & 15, fq = lane >> 4;
  const int frx = (fr & 7) << 3;

  for (int kt = 0; kt < HD; kt += 64) {
    __syncthreads();
#pragma unroll
    for (int c = 0; c < 4; ++c) async16(gA[c] + kt, lA + c * 2048);
#pragma unroll
    for (int c = 0; c < 2; ++c) {
      async16(gU[c] + kt, lU + c * 2048);
      async16(gG[c] + kt, lG + c * 2048);
    }
    __syncthreads();
#pragma unroll
    for (int kk = 0; kk < 64; kk += 32) {
      short8 af[4], bu[2], bg[2];
      const int kphys = (kk + fq * 8) ^ frx;
#pragma unroll
      for (int mi = 0; mi < 4; ++mi)
        af[mi] = *(const short8*)(As + ((wr * 64 + mi * 16 + fr) << 6) + kphys);
#pragma unroll
      for (int ni = 0; ni < 2; ++ni) {
        bu[ni] = *(const short8*)(Bu + ((wc * 32 + ni * 16 + fr) << 6) + kphys);
        bg[ni] = *(const short8*)(Bg + ((wc * 32 + ni * 16 + fr) << 6) + kphys);
      }
#pragma unroll
      for (int mi = 0; mi < 4; ++mi)
#pragma unroll
        for (int ni = 0; ni < 2; ++ni) {
          accU[mi][ni] = __builtin_amdgcn_mfma_f32_16x16x32_bf16(af[mi], bu[ni], accU[mi][ni], 0, 0, 0);
          accG[mi][ni] = __builtin_amdgcn_mfma_f32_16x16x32_bf16(af[mi], bg[ni], accG[mi][ni], 0, 0, 0);
        }
    }
  }
#pragma unroll
  for (int mi = 0; mi < 4; ++mi) {
#pragma unroll
    for (int q = 0; q < 4; ++q) {
      int grow = m0 + wr * 64 + mi * 16 + fq * 4 + q;
      if (grow < count) {
        unsigned sg = sgbits[ecap + grow];
        unsigned short* arow = act + (size_t)(ecap + grow) * FD + n0 + wc * 32 + fr;
#pragma unroll
        for (int ni = 0; ni < 2; ++ni) {
          int gcol = n0 + wc * 32 + ni * 16 + fr;
          float a = accU[mi][ni][q] * fmaxf(accG[mi][ni][q], 0.f);
          a = ((sg >> (gcol / 96)) & 1u) ? a : 0.f;
          arow[ni * 16] = f2bf(a);
        }
      }
    }
  }
}

// ---------------- down GEMM (single-buffer) -> per-slot bf16 rows ----------------
__global__ __launch_bounds__(256, 3) void down_bf16(
    const unsigned short* __restrict__ act, const unsigned short* __restrict__ wdb,
    const int* __restrict__ counts, unsigned short* __restrict__ act_dn) {
  const int hw = blockIdx.x;
  const int idx = (hw & 7) * (DNGRID / 8) + (hw >> 3);
  const int ti = idx >> 4, nb = idx & 15;
  int e, m0, count;
  tile_from_counts(counts, ti, e, m0, count);
  if (e < 0) return;
  const int n0 = nb * 128;

  __shared__ __align__(16) unsigned short As[128 * 64];
  __shared__ __align__(16) unsigned short Bs[128 * 64];

  const int tid = threadIdx.x, lane = tid & 63, wid = tid >> 6;
  const int wr = wid >> 1, wc = wid & 1;
  const int ecap = e * CAPE;

  const int srow = tid >> 3, sblk = tid & 7;
  const unsigned short *gA[4], *gB[4];
#pragma unroll
  for (int c = 0; c < 4; ++c) {
    int r = c * 32 + srow;
    int gr = m0 + r;
    if (gr > CAPE - 1) gr = CAPE - 1;
    int swz = (sblk ^ (r & 7)) << 3;
    gA[c] = act + (size_t)(ecap + gr) * FD + swz;
    gB[c] = wdb + (size_t)(e * HD + n0 + r) * FD + swz;
  }
  unsigned short* lA = As + (tid << 3);
  unsigned short* lB = Bs + (tid << 3);

  f32x4 accD[4][4];
#pragma unroll
  for (int i = 0; i < 4; ++i)
#pragma unroll
    for (int j = 0; j < 4; ++j) accD[i][j] = (f32x4)0.f;

  const int fr = lane & 15, fq = lane >> 4;
  const int frx = (fr & 7) << 3;

  for (int kt = 0; kt < FD; kt += 64) {
    __syncthreads();
#pragma unroll
    for (int c = 0; c < 4; ++c) {
      async16(gA[c] + kt, lA + c * 2048);
      async16(gB[c] + kt, lB + c * 2048);
    }
    __syncthreads();
#pragma unroll
    for (int kk = 0; kk < 64; kk += 32) {
      short8 af[4], bb[4];
      const int kphys = (kk + fq * 8) ^ frx;
#pragma unroll
      for (int mi = 0; mi < 4; ++mi)
        af[mi] = *(const short8*)(As + ((wr * 64 + mi * 16 + fr) << 6) + kphys);
#pragma unroll
      for (int ni = 0; ni < 4; ++ni)
        bb[ni] = *(const short8*)(Bs + ((wc * 64 + ni * 16 + fr) << 6) + kphys);
#pragma unroll
      for (int mi = 0; mi < 4; ++mi)
#pragma unroll
        for (int ni = 0; ni < 4; ++ni)
          accD[mi][ni] = __builtin_amdgcn_mfma_f32_16x16x32_bf16(af[mi], bb[ni], accD[mi][ni], 0, 0, 0);
    }
  }
#pragma unroll
  for (int mi = 0; mi < 4; ++mi) {
#pragma unroll
    for (int q = 0; q < 4; ++q) {
      int grow = m0 + wr * 64 + mi * 16 + fq * 4 + q;
      if (grow < count) {
        unsigned short* drow = act_dn + (size_t)(ecap + grow) * HD + n0 + wc * 64 + fr;
#pragma unroll
        for (int ni = 0; ni < 4; ++ni)
          drow[ni * 16] = f2bf(accD[mi][ni][q]);
      }
    }
  }
}

// ---------------- combine: out[t] = sum_k w[slot] * act_dn[slot] ----------------
__global__ __launch_bounds__(256) void combine_kernel(
    const unsigned short* __restrict__ act_dn, const float* __restrict__ tok_w,
    const int* __restrict__ slotmap, float* __restrict__ outF) {
  const int t = blockIdx.x;
  const int h = threadIdx.x * 8;
  const int4 sm = *(const int4*)(slotmap + t * TOPK);
  float acc[8];
#pragma unroll
  for (int j = 0; j < 8; ++j) acc[j] = 0.f;
  const int ss[4] = {sm.x, sm.y, sm.z, sm.w};
#pragma unroll
  for (int k = 0; k < TOPK; ++k) {
    int s = ss[k];
    if (s >= 0) {
      float w = tok_w[s];
      us8 v = *(const us8*)(act_dn + (size_t)s * HD + h);
#pragma unroll
      for (int j = 0; j < 8; ++j) acc[j] += w * bf2f(v[j]);
    }
  }
  float* op = outF + (size_t)t * HD + h;
  f32x4 o0 = {acc[0], acc[1], acc[2], acc[3]};
  f32x4 o1 = {acc[4], acc[5], acc[6], acc[7]};
  *(f32x4*)op = o0;
  *(f32x4*)(op + 4) = o1;
}

extern "C" void kernel_launch(void* const* d_in, const int* in_sizes, int n_in,
                              void* d_out, int out_size, void* d_ws, size_t ws_size,
                              hipStream_t stream) {
  const float* rin = (const float*)d_in[0];
  const float* x = (const float*)d_in[1];
  const float* w_router = (const float*)d_in[2];
  const float* w_up = (const float*)d_in[3];
  const float* w_gate = (const float*)d_in[4];
  const float* w_down = (const float*)d_in[5];
  const float* w_sg = (const float*)d_in[6];
  float* outF = (float*)d_out;
  float* top_logits = outF + (size_t)TT * HD;

  char* ws = (char*)d_ws;
  int* sel = (int*)(ws + 0);                      // 64 KB
  float* rwts = (float*)(ws + (64 << 10));        // 64 KB
  int* tidx = (int*)(ws + (192 << 10));           // 128 KB
  float* tw = (float*)(ws + (320 << 10));         // 128 KB
  unsigned* sgb = (unsigned*)(ws + (448 << 10));  // 128 KB
  int* counts = (int*)(ws + (576 << 10));
  int* slotmap = (int*)(ws + (1152 << 10));       // 64 KB
  unsigned short* act = (unsigned short*)(ws + ((size_t)2 << 20));   // 48 MB
  unsigned short* xb = (unsigned short*)(ws + ((size_t)52 << 20));   // 16 MB
  unsigned short* wub = (unsigned short*)(ws + ((size_t)69 << 20));  // 96 MB
  unsigned short* wgb = wub + (size_t)NE * HD * FD;                  // 96 MB
  unsigned short* wdb = wgb + (size_t)NE * HD * FD;                  // 96 MB
  unsigned short* act_dn = wub;  // overlays wub+wgb (dead once down_bf16 runs)

  // routing front-end + x conversion
  cvt_x_kernel<<<(TT * HD) / (256 * 8), 256, 0, stream>>>(x, xb);
  logits_kernel<<<TT / 16, 256, 0, stream>>>(rin, w_router, top_logits, sel, rwts);
  dispatch_kernel<<<NE, 256, 0, stream>>>(sel, rwts, tidx, tw, counts, slotmap);
  sgate_kernel<<<dim3(CAPE / 128, NE), 256, 0, stream>>>(rin, w_sg, tidx, counts, sgb);

  // weight prepasses: w_down FIRST so up/gate bf16 weights are L3-hot for up_gate
  transpose_cvt_kernel<<<dim3(FD / 64, HD / 64, NE), 256, 0, stream>>>(w_down, wdb, FD, HD);
  transpose_cvt2_kernel<<<dim3(HD / 64, FD / 64, NE), 256, 0, stream>>>(w_up, w_gate, wub, wgb, HD, FD);

  // expert GEMMs (work-list balance derived in-kernel from counts)
  up_gate_bf16<<<UPGRID, 256, 0, stream>>>(xb, wub, wgb, tidx, counts, sgb, act);
  down_bf16<<<DNGRID, 256, 0, stream>>>(act, wdb, counts, act_dn);
  combine_kernel<<<TT, 256, 0, stream>>>(act_dn, tw, slotmap, outF);
}